// Round 3
// baseline (132.835 us; speedup 1.0000x reference)
//
#include <hip/hip_runtime.h>
#include <math.h>

#define N 4096
#define B 2048
#define RANK 4
#define ALPHA 0.8862269254527580f   // sqrt(pi)/2
#define INV_N (1.0f / 4096.0f)

#define RPB1 8                      // rows per block, kernel 1
#define SPLITS1 (N / RPB1)          // 512 partial splits
#define RPB3 16                     // rows per block, kernel 3

// ---------------------------------------------------------------------------
// Kernel 1: rank-4 (+z) partial reduction, CONTIGUOUS-SLAB access.
// 512 blocks x 256 thr; block owns 8 whole rows = 64 KB contiguous of h.
// Flat slab index 4t + 1024k: row = k>>1 (wave-uniform), col = 4t or 4t+1024
// -> each thread accumulates two column-sets (aA at 4t, aB at 4t+1024).
// Wave access = 1 KB contiguous, block footprint contiguous: the m13-proven
// streaming pattern (vs R0/R2's 8KB-strided column-window streams).
// ---------------------------------------------------------------------------
__global__ __launch_bounds__(256) void k_reduce_partial(
    const float* __restrict__ h, const float* __restrict__ v,
    const float* __restrict__ z, float* __restrict__ partials) {
  __shared__ float lv[RPB1 * RANK];  // 32 floats
  __shared__ float lz[RPB1];
  const int tid = threadIdx.x;
  const int row0 = blockIdx.x * RPB1;

  if (tid < RPB1 * RANK) {
    lv[tid] = v[row0 * RANK + tid];
  } else if (tid < RPB1 * RANK + RPB1) {
    lz[tid - RPB1 * RANK] = z[row0 + (tid - RPB1 * RANK)];
  }
  __syncthreads();

  float4 zero = {0.f, 0.f, 0.f, 0.f};
  float4 aA[5] = {zero, zero, zero, zero, zero};
  float4 aB[5] = {zero, zero, zero, zero, zero};

  const float* hp = h + (size_t)row0 * B + tid * 4;
#pragma unroll
  for (int r = 0; r < RPB1; ++r) {
    const float4 h0 = *(const float4*)(hp + (size_t)(2 * r) * 1024);
    const float4 h1 = *(const float4*)(hp + (size_t)(2 * r + 1) * 1024);
    float4 p0, p1;
    p0.x = erff(ALPHA * h0.x); p0.y = erff(ALPHA * h0.y);
    p0.z = erff(ALPHA * h0.z); p0.w = erff(ALPHA * h0.w);
    p1.x = erff(ALPHA * h1.x); p1.y = erff(ALPHA * h1.y);
    p1.z = erff(ALPHA * h1.z); p1.w = erff(ALPHA * h1.w);
    const float v0 = lv[r * 4 + 0], v1 = lv[r * 4 + 1];
    const float v2 = lv[r * 4 + 2], v3 = lv[r * 4 + 3];
    const float zr = lz[r];
    aA[0].x = fmaf(v0, p0.x, aA[0].x); aA[0].y = fmaf(v0, p0.y, aA[0].y);
    aA[0].z = fmaf(v0, p0.z, aA[0].z); aA[0].w = fmaf(v0, p0.w, aA[0].w);
    aA[1].x = fmaf(v1, p0.x, aA[1].x); aA[1].y = fmaf(v1, p0.y, aA[1].y);
    aA[1].z = fmaf(v1, p0.z, aA[1].z); aA[1].w = fmaf(v1, p0.w, aA[1].w);
    aA[2].x = fmaf(v2, p0.x, aA[2].x); aA[2].y = fmaf(v2, p0.y, aA[2].y);
    aA[2].z = fmaf(v2, p0.z, aA[2].z); aA[2].w = fmaf(v2, p0.w, aA[2].w);
    aA[3].x = fmaf(v3, p0.x, aA[3].x); aA[3].y = fmaf(v3, p0.y, aA[3].y);
    aA[3].z = fmaf(v3, p0.z, aA[3].z); aA[3].w = fmaf(v3, p0.w, aA[3].w);
    aA[4].x = fmaf(zr, p0.x, aA[4].x); aA[4].y = fmaf(zr, p0.y, aA[4].y);
    aA[4].z = fmaf(zr, p0.z, aA[4].z); aA[4].w = fmaf(zr, p0.w, aA[4].w);
    aB[0].x = fmaf(v0, p1.x, aB[0].x); aB[0].y = fmaf(v0, p1.y, aB[0].y);
    aB[0].z = fmaf(v0, p1.z, aB[0].z); aB[0].w = fmaf(v0, p1.w, aB[0].w);
    aB[1].x = fmaf(v1, p1.x, aB[1].x); aB[1].y = fmaf(v1, p1.y, aB[1].y);
    aB[1].z = fmaf(v1, p1.z, aB[1].z); aB[1].w = fmaf(v1, p1.w, aB[1].w);
    aB[2].x = fmaf(v2, p1.x, aB[2].x); aB[2].y = fmaf(v2, p1.y, aB[2].y);
    aB[2].z = fmaf(v2, p1.z, aB[2].z); aB[2].w = fmaf(v2, p1.w, aB[2].w);
    aB[3].x = fmaf(v3, p1.x, aB[3].x); aB[3].y = fmaf(v3, p1.y, aB[3].y);
    aB[3].z = fmaf(v3, p1.z, aB[3].z); aB[3].w = fmaf(v3, p1.w, aB[3].w);
    aB[4].x = fmaf(zr, p1.x, aB[4].x); aB[4].y = fmaf(zr, p1.y, aB[4].y);
    aB[4].z = fmaf(zr, p1.z, aB[4].z); aB[4].w = fmaf(zr, p1.w, aB[4].w);
  }

  float* pp = partials + (size_t)blockIdx.x * 5 * B + tid * 4;
#pragma unroll
  for (int r = 0; r < 5; ++r) {
    *(float4*)(pp + (size_t)r * B) = aA[r];
    *(float4*)(pp + (size_t)r * B + 1024) = aB[r];
  }
}

// ---------------------------------------------------------------------------
// Kernel 2: sum SPLITS1 partials -> s[4][B] (ws) and y[B] (d_out).
// 5*B outputs, one thread each; wave reads are 256 B coalesced per split.
// ~21 MB, L2/L3-resident, 40 blocks with unroll-16 independent loads.
// ---------------------------------------------------------------------------
__global__ __launch_bounds__(256) void k_reduce_final(
    const float* __restrict__ partials, float* __restrict__ sfin,
    float* __restrict__ y) {
  const int o = blockIdx.x * 256 + threadIdx.x;  // [0, 5*B)
  const int r = o / B;
  const int b = o - r * B;
  float s = 0.f;
#pragma unroll 16
  for (int sp = 0; sp < SPLITS1; ++sp)
    s += partials[((size_t)sp * 5 + r) * B + b];
  if (r < RANK)
    sfin[(size_t)r * B + b] = s;
  else
    y[b] = s * INV_N;  // y = (z.T @ phi) / N
}

// ---------------------------------------------------------------------------
// Kernel 3: h_new[n][b] = (sum_r u[n][r]*s[r][b])/N + m[n]*x[b]
// (DT/TAU = 1 -> h cancels exactly; h is never read.)
// 256 blocks x 256 thr; block owns 16 whole rows = 128 KB CONTIGUOUS stores.
// Same two-column-set trick as k1; u/m are broadcast loads (wave-uniform n).
// ---------------------------------------------------------------------------
__global__ __launch_bounds__(256) void k_update(
    const float* __restrict__ sfin, const float* __restrict__ u,
    const float* __restrict__ m, const float* __restrict__ x,
    float* __restrict__ hnew) {
  const int tid = threadIdx.x;
  const int row0 = blockIdx.x * RPB3;
  const int c0 = tid * 4;

  const float4 sA0 = *(const float4*)(sfin + 0 * B + c0);
  const float4 sA1 = *(const float4*)(sfin + 1 * B + c0);
  const float4 sA2 = *(const float4*)(sfin + 2 * B + c0);
  const float4 sA3 = *(const float4*)(sfin + 3 * B + c0);
  const float4 xa  = *(const float4*)(x + c0);
  const float4 sB0 = *(const float4*)(sfin + 0 * B + c0 + 1024);
  const float4 sB1 = *(const float4*)(sfin + 1 * B + c0 + 1024);
  const float4 sB2 = *(const float4*)(sfin + 2 * B + c0 + 1024);
  const float4 sB3 = *(const float4*)(sfin + 3 * B + c0 + 1024);
  const float4 xb  = *(const float4*)(x + c0 + 1024);

  float* op = hnew + (size_t)row0 * B + c0;
#pragma unroll
  for (int i = 0; i < RPB3; ++i) {
    const int n = row0 + i;
    const float4 uv = *(const float4*)(u + (size_t)n * RANK);
    const float mv = m[n];
    float4 oA, oB;
    oA.x = fmaf(mv, xa.x,
                (sA0.x * uv.x + sA1.x * uv.y + sA2.x * uv.z + sA3.x * uv.w) * INV_N);
    oA.y = fmaf(mv, xa.y,
                (sA0.y * uv.x + sA1.y * uv.y + sA2.y * uv.z + sA3.y * uv.w) * INV_N);
    oA.z = fmaf(mv, xa.z,
                (sA0.z * uv.x + sA1.z * uv.y + sA2.z * uv.z + sA3.z * uv.w) * INV_N);
    oA.w = fmaf(mv, xa.w,
                (sA0.w * uv.x + sA1.w * uv.y + sA2.w * uv.z + sA3.w * uv.w) * INV_N);
    oB.x = fmaf(mv, xb.x,
                (sB0.x * uv.x + sB1.x * uv.y + sB2.x * uv.z + sB3.x * uv.w) * INV_N);
    oB.y = fmaf(mv, xb.y,
                (sB0.y * uv.x + sB1.y * uv.y + sB2.y * uv.z + sB3.y * uv.w) * INV_N);
    oB.z = fmaf(mv, xb.z,
                (sB0.z * uv.x + sB1.z * uv.y + sB2.z * uv.z + sB3.z * uv.w) * INV_N);
    oB.w = fmaf(mv, xb.w,
                (sB0.w * uv.x + sB1.w * uv.y + sB2.w * uv.z + sB3.w * uv.w) * INV_N);
    *(float4*)(op + (size_t)i * B) = oA;
    *(float4*)(op + (size_t)i * B + 1024) = oB;
  }
}

// ---------------------------------------------------------------------------
extern "C" void kernel_launch(void* const* d_in, const int* in_sizes, int n_in,
                              void* d_out, int out_size, void* d_ws,
                              size_t ws_size, hipStream_t stream) {
  const float* x = (const float*)d_in[0];  // [1, B]
  const float* h = (const float*)d_in[1];  // [N, B]
  const float* m = (const float*)d_in[2];  // [N, 1]
  const float* u = (const float*)d_in[3];  // [N, RANK]
  const float* v = (const float*)d_in[4];  // [N, RANK]
  const float* z = (const float*)d_in[5];  // [N, 1]

  float* y = (float*)d_out;            // output 0: y [1, B]
  float* hnew = (float*)d_out + B;     // output 1: h_new [N, B]

  float* partials = (float*)d_ws;                          // [SPLITS1][5][B]
  float* sfin = (float*)d_ws + (size_t)SPLITS1 * 5 * B;    // [RANK][B]
  // ws usage: (512*5*2048 + 4*2048) * 4 B = ~21 MB

  k_reduce_partial<<<SPLITS1, 256, 0, stream>>>(h, v, z, partials);
  k_reduce_final<<<(5 * B) / 256, 256, 0, stream>>>(partials, sfin, y);
  k_update<<<N / RPB3, 256, 0, stream>>>(sfin, u, m, x, hnew);
}

// Round 5
// 116.817 us; speedup vs baseline: 1.1371x; 1.1371x over previous
//
#include <hip/hip_runtime.h>
#include <math.h>

#define N 4096
#define B 2048
#define RANK 4
#define ALPHA 0.8862269254527580f   // sqrt(pi)/2
#define INV_N (1.0f / 4096.0f)

#define RPB1 16                     // rows per block, kernel 1
#define SPLITS (N / RPB1)           // 256 partial splits
#define P (5 * B)                   // one partial plane = 10240 floats
#define CH 8                        // stage-A chunks
#define SPC (SPLITS / CH)           // 32 splits per stage-A chunk
#define RPB3 4                      // rows per block, kernel 3

// raw vector type: __builtin_nontemporal_* requires ext_vector_type,
// not HIP_vector_type<float,4>
typedef float vf4 __attribute__((ext_vector_type(4)));

// ---------------------------------------------------------------------------
// Kernel 1: rank-4 (+z) partial reduction.
// 256 blocks x 512 thr -> exactly 1 block/CU, no tail. Block owns 16 whole
// rows = 128 KB contiguous of h. Thread t owns cols 4t..4t+3 (512*4 = 2048
// covers the full row), 16 fully-unrolled nontemporal vf4 loads
// (16 KB/wave in flight; HBM latency needs ~9 KB/CU). v/z staged in LDS
// (wave-uniform broadcast). Writes partials[split][5][B] coalesced.
// ---------------------------------------------------------------------------
__global__ __launch_bounds__(512) void k_reduce_partial(
    const float* __restrict__ h, const float* __restrict__ v,
    const float* __restrict__ z, float* __restrict__ partials) {
  __shared__ float lv[RPB1 * RANK];  // 64 floats
  __shared__ float lz[RPB1];
  const int tid = threadIdx.x;
  const int row0 = blockIdx.x * RPB1;

  if (tid < RPB1 * RANK) {
    lv[tid] = v[row0 * RANK + tid];
  } else if (tid < RPB1 * RANK + RPB1) {
    lz[tid - RPB1 * RANK] = z[row0 + (tid - RPB1 * RANK)];
  }
  __syncthreads();

  vf4 a0 = {0.f, 0.f, 0.f, 0.f};
  vf4 a1 = a0, a2 = a0, a3 = a0, a4 = a0;

  const float* hp = h + (size_t)row0 * B + tid * 4;
#pragma unroll
  for (int r = 0; r < RPB1; ++r) {
    const vf4 hv =
        __builtin_nontemporal_load((const vf4*)(hp + (size_t)r * B));
    vf4 p;
    p.x = erff(ALPHA * hv.x);
    p.y = erff(ALPHA * hv.y);
    p.z = erff(ALPHA * hv.z);
    p.w = erff(ALPHA * hv.w);
    const float v0 = lv[r * 4 + 0], v1 = lv[r * 4 + 1];
    const float v2 = lv[r * 4 + 2], v3 = lv[r * 4 + 3];
    const float zr = lz[r];
    a0.x = fmaf(v0, p.x, a0.x); a0.y = fmaf(v0, p.y, a0.y);
    a0.z = fmaf(v0, p.z, a0.z); a0.w = fmaf(v0, p.w, a0.w);
    a1.x = fmaf(v1, p.x, a1.x); a1.y = fmaf(v1, p.y, a1.y);
    a1.z = fmaf(v1, p.z, a1.z); a1.w = fmaf(v1, p.w, a1.w);
    a2.x = fmaf(v2, p.x, a2.x); a2.y = fmaf(v2, p.y, a2.y);
    a2.z = fmaf(v2, p.z, a2.z); a2.w = fmaf(v2, p.w, a2.w);
    a3.x = fmaf(v3, p.x, a3.x); a3.y = fmaf(v3, p.y, a3.y);
    a3.z = fmaf(v3, p.z, a3.z); a3.w = fmaf(v3, p.w, a3.w);
    a4.x = fmaf(zr, p.x, a4.x); a4.y = fmaf(zr, p.y, a4.y);
    a4.z = fmaf(zr, p.z, a4.z); a4.w = fmaf(zr, p.w, a4.w);
  }

  float* pp = partials + (size_t)blockIdx.x * P + tid * 4;
  *(vf4*)(pp + 0 * B) = a0;
  *(vf4*)(pp + 1 * B) = a1;
  *(vf4*)(pp + 2 * B) = a2;
  *(vf4*)(pp + 3 * B) = a3;
  *(vf4*)(pp + 4 * B) = a4;
}

// ---------------------------------------------------------------------------
// Kernel 2a: stage-A tree reduce: 256 splits -> 8 chunk-partials.
// grid (P/256, CH) = (40, 8) = 320 blocks. Thread owns one flat index f of
// the [5][B] plane; sums 32 splits (1 KB-coalesced per wave per iteration,
// 40 KB stride, unrolled -> independent loads). Output 320 KB (L2-resident).
// ---------------------------------------------------------------------------
__global__ __launch_bounds__(256) void k_reduce_a(
    const float* __restrict__ partials, float* __restrict__ partial2) {
  const int f = blockIdx.x * 256 + threadIdx.x;  // [0, P)
  const int j = blockIdx.y;                      // chunk
  const float* pp = partials + (size_t)(j * SPC) * P + f;
  float s = 0.f;
#pragma unroll 8
  for (int sp = 0; sp < SPC; ++sp)
    s += pp[(size_t)sp * P];
  partial2[(size_t)j * P + f] = s;
}

// ---------------------------------------------------------------------------
// Kernel 2b: stage-B: sum 8 chunk-partials -> s[4][B] (ws) and y[B] (d_out).
// ---------------------------------------------------------------------------
__global__ __launch_bounds__(256) void k_reduce_b(
    const float* __restrict__ partial2, float* __restrict__ sfin,
    float* __restrict__ y) {
  const int f = blockIdx.x * 256 + threadIdx.x;  // [0, P)
  float s = 0.f;
#pragma unroll
  for (int j = 0; j < CH; ++j)
    s += partial2[(size_t)j * P + f];
  if (f < RANK * B)
    sfin[f] = s;
  else
    y[f - RANK * B] = s * INV_N;  // y = (z.T @ phi) / N
}

// ---------------------------------------------------------------------------
// Kernel 3: h_new[n][b] = (sum_r u[n][r]*s[r][b])/N + m[n]*x[b]
// (DT/TAU = 1 -> h cancels exactly; h is never read.)
// 1024 blocks x 256 thr (4 blocks/CU, 16 waves/CU); block owns 4 whole rows
// = 32 KB contiguous nontemporal store slab. Thread t owns cols 4t and
// 4t+1024; s/x hoisted; u/m broadcast loads (wave-uniform n).
// ---------------------------------------------------------------------------
__global__ __launch_bounds__(256) void k_update(
    const float* __restrict__ sfin, const float* __restrict__ u,
    const float* __restrict__ m, const float* __restrict__ x,
    float* __restrict__ hnew) {
  const int tid = threadIdx.x;
  const int row0 = blockIdx.x * RPB3;
  const int c0 = tid * 4;

  const vf4 sA0 = *(const vf4*)(sfin + 0 * B + c0);
  const vf4 sA1 = *(const vf4*)(sfin + 1 * B + c0);
  const vf4 sA2 = *(const vf4*)(sfin + 2 * B + c0);
  const vf4 sA3 = *(const vf4*)(sfin + 3 * B + c0);
  const vf4 xa  = *(const vf4*)(x + c0);
  const vf4 sB0 = *(const vf4*)(sfin + 0 * B + c0 + 1024);
  const vf4 sB1 = *(const vf4*)(sfin + 1 * B + c0 + 1024);
  const vf4 sB2 = *(const vf4*)(sfin + 2 * B + c0 + 1024);
  const vf4 sB3 = *(const vf4*)(sfin + 3 * B + c0 + 1024);
  const vf4 xb  = *(const vf4*)(x + c0 + 1024);

  float* op = hnew + (size_t)row0 * B + c0;
#pragma unroll
  for (int i = 0; i < RPB3; ++i) {
    const int n = row0 + i;
    const vf4 uv = *(const vf4*)(u + (size_t)n * RANK);
    const float mv = m[n];
    vf4 oA, oB;
    oA.x = fmaf(mv, xa.x,
                (sA0.x * uv.x + sA1.x * uv.y + sA2.x * uv.z + sA3.x * uv.w) * INV_N);
    oA.y = fmaf(mv, xa.y,
                (sA0.y * uv.x + sA1.y * uv.y + sA2.y * uv.z + sA3.y * uv.w) * INV_N);
    oA.z = fmaf(mv, xa.z,
                (sA0.z * uv.x + sA1.z * uv.y + sA2.z * uv.z + sA3.z * uv.w) * INV_N);
    oA.w = fmaf(mv, xa.w,
                (sA0.w * uv.x + sA1.w * uv.y + sA2.w * uv.z + sA3.w * uv.w) * INV_N);
    oB.x = fmaf(mv, xb.x,
                (sB0.x * uv.x + sB1.x * uv.y + sB2.x * uv.z + sB3.x * uv.w) * INV_N);
    oB.y = fmaf(mv, xb.y,
                (sB0.y * uv.x + sB1.y * uv.y + sB2.y * uv.z + sB3.y * uv.w) * INV_N);
    oB.z = fmaf(mv, xb.z,
                (sB0.z * uv.x + sB1.z * uv.y + sB2.z * uv.z + sB3.z * uv.w) * INV_N);
    oB.w = fmaf(mv, xb.w,
                (sB0.w * uv.x + sB1.w * uv.y + sB2.w * uv.z + sB3.w * uv.w) * INV_N);
    __builtin_nontemporal_store(oA, (vf4*)(op + (size_t)i * B));
    __builtin_nontemporal_store(oB, (vf4*)(op + (size_t)i * B + 1024));
  }
}

// ---------------------------------------------------------------------------
extern "C" void kernel_launch(void* const* d_in, const int* in_sizes, int n_in,
                              void* d_out, int out_size, void* d_ws,
                              size_t ws_size, hipStream_t stream) {
  const float* x = (const float*)d_in[0];  // [1, B]
  const float* h = (const float*)d_in[1];  // [N, B]
  const float* m = (const float*)d_in[2];  // [N, 1]
  const float* u = (const float*)d_in[3];  // [N, RANK]
  const float* v = (const float*)d_in[4];  // [N, RANK]
  const float* z = (const float*)d_in[5];  // [N, 1]

  float* y = (float*)d_out;            // output 0: y [1, B]
  float* hnew = (float*)d_out + B;     // output 1: h_new [N, B]

  float* partials = (float*)d_ws;                       // [SPLITS][5][B] 10.5 MB
  float* partial2 = partials + (size_t)SPLITS * P;      // [CH][5][B]     320 KB
  float* sfin = partial2 + (size_t)CH * P;              // [RANK][B]       32 KB

  k_reduce_partial<<<SPLITS, 512, 0, stream>>>(h, v, z, partials);
  k_reduce_a<<<dim3(P / 256, CH), 256, 0, stream>>>(partials, partial2);
  k_reduce_b<<<P / 256, 256, 0, stream>>>(partial2, sfin, y);
  k_update<<<N / RPB3, 256, 0, stream>>>(sfin, u, m, x, hnew);
}